// Round 7
// baseline (2791.652 us; speedup 1.0000x reference)
//
#include <hip/hip_runtime.h>
#include <hip/hip_bf16.h>

#define N_V 100000
#define N_E 20000
#define N_P 1600000
#define FDIM 128
#define HDIM 128
#define BN_EPS 1e-5f

// ---- bucket/sort geometry ----
#define SORT_C 4096
#define SORT_BLOCKS ((N_P + SORT_C - 1) / SORT_C)   // 391
#define NB_E 313                   // edge buckets (64 edges each)
#define EB_SHIFT 6
#define EB_REGION 9216             // slots per edge bucket region
#define NB_V 391                   // vertex buckets (256 vertices each)
#define VB_SHIFT 8
#define VB_REGION 8192
#define SENTINEL 0xFFFFFFFFu

typedef __attribute__((ext_vector_type(8))) short short8;
typedef __attribute__((ext_vector_type(4))) float floatx4;

__device__ __forceinline__ float bf_lo(unsigned u) {
    return __uint_as_float(u << 16);
}
__device__ __forceinline__ float bf_hi(unsigned u) {
    return __uint_as_float(u & 0xffff0000u);
}
// fp32 -> bf16 bits, round-to-nearest-even
__device__ __forceinline__ unsigned short f2bf(float f) {
    unsigned u = __float_as_uint(f);
    return (unsigned short)((u + 0x7fffu + ((u >> 16) & 1u)) >> 16);
}

// ---------------------------------------------------------------------------
// Kernel A: h = X @ W + b via bf16 MFMA, computed as C^T = W^T · X^T.
// ---------------------------------------------------------------------------
#define GEMM_BLOCKS 625
#define WT_STRIDE 136   // 128 + 8 bf16 pad -> 2-way-only LDS conflicts
__global__ __launch_bounds__(256) void k_gemm_mfma(
    const float* __restrict__ X, const float* __restrict__ W,
    const float* __restrict__ bias, unsigned* __restrict__ h_u) {
    __shared__ unsigned short WTs[FDIM * WT_STRIDE];   // ~34 KB
    const int t = threadIdx.x;
    for (int idx = t; idx < FDIM * HDIM; idx += 256) {
        const int k = idx >> 7, m = idx & 127;
        WTs[m * WT_STRIDE + k] = f2bf(W[idx]);
    }
    __syncthreads();

    const int wave = t >> 6, lane = t & 63;
    const int quad = lane >> 4, sub = lane & 15;
    const int nstrips = N_V / 16;  // 6250, exact

    for (int s = blockIdx.x * 4 + wave; s < nstrips; s += GEMM_BLOCKS * 4) {
        const int row0 = s * 16;
        short8 xf[4];
        const float* xp = X + (size_t)(row0 + sub) * FDIM + quad * 8;
        #pragma unroll
        for (int kt = 0; kt < 4; ++kt) {
            const float4 a = *(const float4*)(xp + kt * 32);
            const float4 b2 = *(const float4*)(xp + kt * 32 + 4);
            short8 f;
            f[0] = (short)f2bf(a.x);  f[1] = (short)f2bf(a.y);
            f[2] = (short)f2bf(a.z);  f[3] = (short)f2bf(a.w);
            f[4] = (short)f2bf(b2.x); f[5] = (short)f2bf(b2.y);
            f[6] = (short)f2bf(b2.z); f[7] = (short)f2bf(b2.w);
            xf[kt] = f;
        }
        #pragma unroll
        for (int tile = 0; tile < 8; ++tile) {
            floatx4 acc = {0.f, 0.f, 0.f, 0.f};
            const unsigned short* wp =
                WTs + (tile * 16 + sub) * WT_STRIDE + quad * 8;
            #pragma unroll
            for (int kt = 0; kt < 4; ++kt) {
                const short8 af = *(const short8*)(wp + kt * 32);
                acc = __builtin_amdgcn_mfma_f32_16x16x32_bf16(af, xf[kt], acc,
                                                              0, 0, 0);
            }
            const int ch = tile * 16 + quad * 4;
            const float4 bb = *(const float4*)(bias + ch);
            const float c0 = acc[0] + bb.x, c1 = acc[1] + bb.y;
            const float c2 = acc[2] + bb.z, c3 = acc[3] + bb.w;
            const unsigned lo = (unsigned)f2bf(c0) | ((unsigned)f2bf(c1) << 16);
            const unsigned hi = (unsigned)f2bf(c2) | ((unsigned)f2bf(c3) << 16);
            uint2* dst = (uint2*)(h_u + (size_t)(row0 + sub) * 64 + (ch >> 1));
            *dst = make_uint2(lo, hi);
        }
    }
}

// ---------------------------------------------------------------------------
// Kernel B: per-channel sum & sumsq of bf16 h.  Vectorized: uint4 per lane
// (8 channels), shfl reduce across row-lanes, one LDS+global atomic pass.
// ---------------------------------------------------------------------------
#define BN_BLOCKS 400
#define BN_RPB 250
__global__ __launch_bounds__(256) void k_bn_stats(
    const unsigned* __restrict__ h_u, float* __restrict__ sums /* [256] */) {
    const int t = threadIdx.x;
    const int c8 = t & 15;            // channel octet: ch 8*c8 .. 8*c8+7
    const int rw = t >> 4;            // 16 row lanes
    const int r0 = blockIdx.x * BN_RPB;
    const int r1 = min(r0 + BN_RPB, N_V);
    float s[8] = {0.f,0.f,0.f,0.f,0.f,0.f,0.f,0.f};
    float ss[8] = {0.f,0.f,0.f,0.f,0.f,0.f,0.f,0.f};
    for (int r = r0 + rw; r < r1; r += 16) {
        const uint4 u = *(const uint4*)(h_u + (size_t)r * 64 + c8 * 4);
        const float x0 = bf_lo(u.x), x1 = bf_hi(u.x);
        const float x2 = bf_lo(u.y), x3 = bf_hi(u.y);
        const float x4 = bf_lo(u.z), x5 = bf_hi(u.z);
        const float x6 = bf_lo(u.w), x7 = bf_hi(u.w);
        s[0]+=x0; ss[0]+=x0*x0;  s[1]+=x1; ss[1]+=x1*x1;
        s[2]+=x2; ss[2]+=x2*x2;  s[3]+=x3; ss[3]+=x3*x3;
        s[4]+=x4; ss[4]+=x4*x4;  s[5]+=x5; ss[5]+=x5*x5;
        s[6]+=x6; ss[6]+=x6*x6;  s[7]+=x7; ss[7]+=x7*x7;
    }
    #pragma unroll
    for (int k = 0; k < 8; ++k) {
        s[k]  += __shfl_xor(s[k], 16);  s[k]  += __shfl_xor(s[k], 32);
        ss[k] += __shfl_xor(ss[k], 16); ss[k] += __shfl_xor(ss[k], 32);
    }
    __shared__ float ls[128], lss[128];
    for (int k = t; k < 128; k += 256) { ls[k] = 0.f; lss[k] = 0.f; }
    __syncthreads();
    if ((t & 63) < 16) {
        #pragma unroll
        for (int k = 0; k < 8; ++k) {
            atomicAdd(&ls[c8 * 8 + k], s[k]);
            atomicAdd(&lss[c8 * 8 + k], ss[k]);
        }
    }
    __syncthreads();
    if (t < 128) {
        atomicAdd(&sums[t],       ls[t]);
        atomicAdd(&sums[128 + t], lss[t]);
    }
}

// ---------------------------------------------------------------------------
// Kernel C: finalize BN -> scale/shift
// ---------------------------------------------------------------------------
__global__ void k_bn_final(const float* __restrict__ sums,
                           const float* __restrict__ gamma,
                           const float* __restrict__ beta,
                           float* __restrict__ scale, float* __restrict__ shift) {
    const int c = threadIdx.x;
    const float inv_n = 1.0f / (float)N_V;
    const float mu  = sums[c] * inv_n;
    const float var = sums[128 + c] * inv_n - mu * mu;
    const float inv = rsqrtf(var + BN_EPS);
    const float sc  = gamma[c] * inv;
    scale[c] = sc;
    shift[c] = beta[c] - mu * sc;
}

// ---------------------------------------------------------------------------
// Kernel D: dual-direction LDS-staged chunk sort, line-aligned full-line
// flush.  One pass over (eid, vid) builds BOTH partitions.
// ---------------------------------------------------------------------------
__global__ __launch_bounds__(256) void k_sort_dual(
    const int* __restrict__ vid, const int* __restrict__ eid,
    int* __restrict__ gcntE, int* __restrict__ gcntV,
    unsigned* __restrict__ partE, unsigned* __restrict__ partV) {
    __shared__ unsigned stageE[SORT_C];          // 16 KB
    __shared__ unsigned stageV[SORT_C];          // 16 KB
    __shared__ int histE[NB_E], curE[NB_E], offsE[NB_E], gbaseE[NB_E];
    __shared__ int histV[NB_V], curV[NB_V], offsV[NB_V], gbaseV[NB_V];
    __shared__ int partial[256];
    const int t = threadIdx.x;
    const int p0 = blockIdx.x * SORT_C;
    const int n = min(SORT_C, N_P - p0);

    for (int k = t; k < NB_E; k += 256) histE[k] = 0;
    for (int k = t; k < NB_V; k += 256) histV[k] = 0;
    __syncthreads();
    for (int i = t; i < n; i += 256) {
        atomicAdd(&histE[((unsigned)eid[p0 + i]) >> EB_SHIFT], 1);
        atomicAdd(&histV[((unsigned)vid[p0 + i]) >> VB_SHIFT], 1);
    }
    __syncthreads();
    // scan E
    {
        constexpr int G = (NB_E + 255) / 256;
        int loc[G]; int s = 0;
        #pragma unroll
        for (int g = 0; g < G; ++g) {
            int idx = t * G + g; loc[g] = s;
            if (idx < NB_E) s += histE[idx];
        }
        partial[t] = s;
        __syncthreads();
        for (int d = 1; d < 256; d <<= 1) {
            int x = (t >= d) ? partial[t - d] : 0;
            __syncthreads(); partial[t] += x; __syncthreads();
        }
        const int base = t ? partial[t - 1] : 0;
        #pragma unroll
        for (int g = 0; g < G; ++g) {
            int idx = t * G + g;
            if (idx < NB_E) { offsE[idx] = base + loc[g]; curE[idx] = base + loc[g]; }
        }
        __syncthreads();
    }
    // scan V
    {
        constexpr int G = (NB_V + 255) / 256;
        int loc[G]; int s = 0;
        #pragma unroll
        for (int g = 0; g < G; ++g) {
            int idx = t * G + g; loc[g] = s;
            if (idx < NB_V) s += histV[idx];
        }
        partial[t] = s;
        __syncthreads();
        for (int d = 1; d < 256; d <<= 1) {
            int x = (t >= d) ? partial[t - d] : 0;
            __syncthreads(); partial[t] += x; __syncthreads();
        }
        const int base = t ? partial[t - 1] : 0;
        #pragma unroll
        for (int g = 0; g < G; ++g) {
            int idx = t * G + g;
            if (idx < NB_V) { offsV[idx] = base + loc[g]; curV[idx] = base + loc[g]; }
        }
        __syncthreads();
    }
    // place both directions
    for (int i = t; i < n; i += 256) {
        const int ev = eid[p0 + i], vv = vid[p0 + i];
        const unsigned pkE = ((unsigned)(ev & 63) << 17) | (unsigned)vv;
        stageE[atomicAdd(&curE[(unsigned)ev >> EB_SHIFT], 1)] = pkE;
        const unsigned pkV = ((unsigned)(vv & 255) << 15) | (unsigned)ev;
        stageV[atomicAdd(&curV[(unsigned)vv >> VB_SHIFT], 1)] = pkV;
    }
    __syncthreads();
    // allocate line-aligned global space
    for (int k = t; k < NB_E; k += 256) {
        const int c = histE[k];
        gbaseE[k] = c ? atomicAdd(&gcntE[k], (c + 15) & ~15) : 0;
    }
    for (int k = t; k < NB_V; k += 256) {
        const int c = histV[k];
        gbaseV[k] = c ? atomicAdd(&gcntV[k], (c + 15) & ~15) : 0;
    }
    __syncthreads();
    // flush E
    for (int k = t >> 3; k < NB_E; k += 32) {
        const int c = histE[k];
        if (c == 0) continue;
        int cpad = (c + 15) & ~15;
        const int gb = gbaseE[k];
        if (gb >= EB_REGION) continue;
        cpad = min(cpad, EB_REGION - gb);
        unsigned* dst = partE + (size_t)k * EB_REGION + gb;
        const int lo = offsE[k];
        for (int j = t & 7; j < cpad; j += 8)
            dst[j] = (j < c) ? stageE[lo + j] : SENTINEL;
    }
    // flush V
    for (int k = t >> 3; k < NB_V; k += 32) {
        const int c = histV[k];
        if (c == 0) continue;
        int cpad = (c + 15) & ~15;
        const int gb = gbaseV[k];
        if (gb >= VB_REGION) continue;
        cpad = min(cpad, VB_REGION - gb);
        unsigned* dst = partV + (size_t)k * VB_REGION + gb;
        const int lo = offsV[k];
        for (int j = t & 7; j < cpad; j += 8)
            dst[j] = (j < c) ? stageV[lo + j] : SENTINEL;
    }
}

// ---------------------------------------------------------------------------
// Kernel F: fused per-bucket edge accumulate (replaces CSR build + gather).
// Block = (edge bucket of 64, channel half); blockIdx%8 pins XCD: XCDs 0-3
// -> half 0, XCDs 4-7 -> half 1 (keeps R5's measured fetch win).  Scans
// partE entries directly, gathers the h half-row (8 lanes x uint4) and
// LDS-atomic-adds into acc[64][65] f32 (pad 65 -> eslot randomizes banks).
// Epilogue: mean + BN scale/shift -> bf16 xe half-row.
// ---------------------------------------------------------------------------
__global__ __launch_bounds__(256) void k_edge_acc(
    const unsigned* __restrict__ h_u, const unsigned* __restrict__ partE,
    const int* __restrict__ gcntE,
    const float* __restrict__ scale, const float* __restrict__ shift,
    unsigned* __restrict__ xe_u) {
    __shared__ float accE[64 * 65];    // 16.6 KB
    __shared__ int cntE[64];
    const int b = blockIdx.x;
    const int xcd = b & 7;
    const int half = xcd >> 2;
    const int bkt = (b >> 3) * 4 + (xcd & 3);
    if (bkt >= NB_E) return;           // block-uniform
    const int t = threadIdx.x;
    const int wave = t >> 6, l = t & 63;
    const int rg = l >> 3, cc = l & 7;   // entry-in-group, channel octet

    for (int k = t; k < 64 * 65; k += 256) accE[k] = 0.f;
    for (int k = t; k < 64; k += 256) cntE[k] = 0;
    __syncthreads();

    const int tot = min(gcntE[bkt], EB_REGION);
    const unsigned* src = partE + (size_t)bkt * EB_REGION;

    for (int i = wave * 8 + rg; i < tot; i += 32) {
        const unsigned a = src[i];
        if (a == SENTINEL) continue;
        const int eslot = (int)(a >> 17);
        const int v = (int)(a & 0x1ffffu);
        const uint4 u =
            *(const uint4*)(h_u + (size_t)v * 64 + half * 32 + cc * 4);
        float* ar = accE + eslot * 65 + cc * 8;
        atomicAdd(ar + 0, bf_lo(u.x)); atomicAdd(ar + 1, bf_hi(u.x));
        atomicAdd(ar + 2, bf_lo(u.y)); atomicAdd(ar + 3, bf_hi(u.y));
        atomicAdd(ar + 4, bf_lo(u.z)); atomicAdd(ar + 5, bf_hi(u.z));
        atomicAdd(ar + 6, bf_lo(u.w)); atomicAdd(ar + 7, bf_hi(u.w));
        if (cc == 0) atomicAdd(&cntE[eslot], 1);
    }
    __syncthreads();

    // epilogue: eslot = t>>2, q = t&3 -> 16 channels each
    const int eslot = t >> 2, q = t & 3;
    const int e = bkt * 64 + eslot;
    if (e < N_E) {
        const int n = cntE[eslot];
        const float rc = (n > 0) ? (1.0f / (float)n) : 0.f;
        unsigned w[8];
        #pragma unroll
        for (int p = 0; p < 8; ++p) {
            const int hc0 = q * 16 + p * 2;
            float m0 = 0.f, m1 = 0.f;
            if (n > 0) {
                m0 = scale[half * 64 + hc0] * accE[eslot * 65 + hc0] * rc +
                     shift[half * 64 + hc0];
                m1 = scale[half * 64 + hc0 + 1] * accE[eslot * 65 + hc0 + 1] * rc +
                     shift[half * 64 + hc0 + 1];
            }
            w[p] = (unsigned)f2bf(m0) | ((unsigned)f2bf(m1) << 16);
        }
        uint4* dst = (uint4*)(xe_u + (size_t)e * 64 + half * 32 + q * 8);
        dst[0] = make_uint4(w[0], w[1], w[2], w[3]);
        dst[1] = make_uint4(w[4], w[5], w[6], w[7]);
    }
}

// ---------------------------------------------------------------------------
// Kernel G: fused per-bucket vertex accumulate + ReLU (replaces CSR build +
// gather).  Block = half a vertex bucket (128 slots), 512 threads,
// acc[128][129] f32 = 66 KB LDS (2 blocks/CU).  Scans partV entries,
// gathers xe full rows (16 lanes x uint4), LDS-adds, epilogue mean+ReLU.
// ---------------------------------------------------------------------------
__global__ __launch_bounds__(512) void k_vert_acc(
    const unsigned* __restrict__ xe_u, const unsigned* __restrict__ partV,
    const int* __restrict__ gcntV, float* __restrict__ out) {
    __shared__ float accV[128 * 129];  // 66 KB
    __shared__ int cntV[128];
    const int b = blockIdx.x;
    const int bkt = b >> 1;
    const int vh = b & 1;
    const int t = threadIdx.x;
    const int wave = t >> 6, l = t & 63;
    const int rg = l >> 4, cc = l & 15;  // entry-in-group, channel octet

    for (int k = t; k < 128 * 129; k += 512) accV[k] = 0.f;
    for (int k = t; k < 128; k += 512) cntV[k] = 0;
    __syncthreads();

    const int tot = min(gcntV[bkt], VB_REGION);
    const unsigned* src = partV + (size_t)bkt * VB_REGION;

    for (int i = wave * 4 + rg; i < tot; i += 32) {
        const unsigned a = src[i];
        if (a == SENTINEL) continue;
        const int vslot = (int)(a >> 15);
        if ((vslot >> 7) != vh) continue;
        const int vs = vslot & 127;
        const int e = (int)(a & 0x7fffu);
        const uint4 u = *(const uint4*)(xe_u + (size_t)e * 64 + cc * 4);
        float* ar = accV + vs * 129 + cc * 8;
        atomicAdd(ar + 0, bf_lo(u.x)); atomicAdd(ar + 1, bf_hi(u.x));
        atomicAdd(ar + 2, bf_lo(u.y)); atomicAdd(ar + 3, bf_hi(u.y));
        atomicAdd(ar + 4, bf_lo(u.z)); atomicAdd(ar + 5, bf_hi(u.z));
        atomicAdd(ar + 6, bf_lo(u.w)); atomicAdd(ar + 7, bf_hi(u.w));
        if (cc == 0) atomicAdd(&cntV[vs], 1);
    }
    __syncthreads();

    // epilogue: 16 vertices per pass x 32 lanes (float4 each), 8 passes
    const int cc2 = t & 31;
    for (int pass = 0; pass < 8; ++pass) {
        const int vs = pass * 16 + (t >> 5);
        const int v = bkt * 256 + vh * 128 + vs;
        if (v >= N_V) continue;
        const float rc = 1.0f / (float)max(cntV[vs], 1);
        const float* ar = accV + vs * 129 + cc2 * 4;
        float4 r;
        r.x = fmaxf(ar[0] * rc, 0.f);
        r.y = fmaxf(ar[1] * rc, 0.f);
        r.z = fmaxf(ar[2] * rc, 0.f);
        r.w = fmaxf(ar[3] * rc, 0.f);
        ((float4*)out)[(size_t)v * 32 + cc2] = r;
    }
}

// ---------------------------------------------------------------------------
extern "C" void kernel_launch(void* const* d_in, const int* in_sizes, int n_in,
                              void* d_out, int out_size, void* d_ws, size_t ws_size,
                              hipStream_t stream) {
    const float* X     = (const float*)d_in[0];
    const int*   vid   = (const int*)d_in[1];
    const int*   eid   = (const int*)d_in[2];
    const float* W     = (const float*)d_in[3];
    const float* b     = (const float*)d_in[4];
    const float* gamma = (const float*)d_in[5];
    const float* beta  = (const float*)d_in[6];
    float* out = (float*)d_out;

    // workspace layout
    char* ws = (char*)d_ws;
    unsigned* h_u   = (unsigned*)ws;  ws += (size_t)N_V * 64 * 4;            // 25.6 MB
    unsigned* xe_u  = (unsigned*)ws;  ws += (size_t)N_E * 64 * 4;            //  5.1 MB
    unsigned* partE = (unsigned*)ws;  ws += (size_t)NB_E * EB_REGION * 4;    // 11.5 MB
    unsigned* partV = (unsigned*)ws;  ws += (size_t)NB_V * VB_REGION * 4;    // 12.8 MB
    // --- zeroed region ---
    char* zbase = ws;
    int*   gcntE = (int*)ws;          ws += (size_t)NB_E * 4;
    int*   gcntV = (int*)ws;          ws += (size_t)NB_V * 4;
    float* sums  = (float*)ws;        ws += 256 * 4;
    // --- end zeroed region ---
    float* scale = (float*)ws;        ws += 128 * 4;
    float* shift = (float*)ws;        ws += 128 * 4;

    hipMemsetAsync(zbase, 0, (size_t)((char*)scale - zbase), stream);

    k_gemm_mfma<<<GEMM_BLOCKS, 256, 0, stream>>>(X, W, b, h_u);
    k_bn_stats<<<BN_BLOCKS, 256, 0, stream>>>(h_u, sums);
    k_bn_final<<<1, 128, 0, stream>>>(sums, gamma, beta, scale, shift);

    k_sort_dual<<<SORT_BLOCKS, 256, 0, stream>>>(vid, eid, gcntE, gcntV,
                                                 partE, partV);

    // fused bucket-accumulate kernels (no CSR build)
    // edge: 80*8 blocks -> (bucket, channel-half) with XCD pinning
    k_edge_acc<<<640, 256, 0, stream>>>(h_u, partE, gcntE, scale, shift, xe_u);
    // vertex: 391 buckets x 2 half-buckets
    k_vert_acc<<<NB_V * 2, 512, 0, stream>>>(xe_u, partV, gcntV, out);
}

// Round 8
// 310.582 us; speedup vs baseline: 8.9885x; 8.9885x over previous
//
#include <hip/hip_runtime.h>
#include <hip/hip_bf16.h>

#define N_V 100000
#define N_E 20000
#define N_P 1600000
#define FDIM 128
#define HDIM 128
#define BN_EPS 1e-5f

// ---- bucket/sort geometry ----
#define SORT_C 4096
#define SORT_BLOCKS ((N_P + SORT_C - 1) / SORT_C)   // 391
#define NB_E 313                   // edge buckets (64 edges each)
#define EB_SHIFT 6
#define EB_REGION 9216             // slots per edge bucket region
#define EB_SORT 5888               // max valid entries per bucket (mean 5112)
#define NB_V 391                   // vertex buckets (256 vertices each)
#define VB_SHIFT 8
#define VB_REGION 8192
#define VB_SORT 4608               // max valid entries per bucket (mean 4096)
#define SENTINEL 0xFFFFFFFFu

#define EIDX_CAP 192   // per-wave LDS index buffer, edges (mean deg 80)
#define VIDX_CAP 64    // per-wave LDS index buffer, vertices (mean deg 16)

typedef __attribute__((ext_vector_type(8))) short short8;
typedef __attribute__((ext_vector_type(4))) float floatx4;

__device__ __forceinline__ float bf_lo(unsigned u) {
    return __uint_as_float(u << 16);
}
__device__ __forceinline__ float bf_hi(unsigned u) {
    return __uint_as_float(u & 0xffff0000u);
}
// fp32 -> bf16 bits, round-to-nearest-even
__device__ __forceinline__ unsigned short f2bf(float f) {
    unsigned u = __float_as_uint(f);
    return (unsigned short)((u + 0x7fffu + ((u >> 16) & 1u)) >> 16);
}

// accumulate 4 bf16 channels from one uint2 into s[0..3]
__device__ __forceinline__ void acc4(float* s, const uint2& u) {
    s[0] += bf_lo(u.x); s[1] += bf_hi(u.x);
    s[2] += bf_lo(u.y); s[3] += bf_hi(u.y);
}

// accumulate 8 bf16 channels from one uint4 into s[0..7]
__device__ __forceinline__ void acc8(float* s, const uint4& u) {
    s[0] += bf_lo(u.x); s[1] += bf_hi(u.x);
    s[2] += bf_lo(u.y); s[3] += bf_hi(u.y);
    s[4] += bf_lo(u.z); s[5] += bf_hi(u.z);
    s[6] += bf_lo(u.w); s[7] += bf_hi(u.w);
}

// ---------------------------------------------------------------------------
// Kernel A: h = X @ W + b via bf16 MFMA, computed as C^T = W^T · X^T.
// ---------------------------------------------------------------------------
#define GEMM_BLOCKS 625
#define WT_STRIDE 136   // 128 + 8 bf16 pad -> 2-way-only LDS conflicts
__global__ __launch_bounds__(256) void k_gemm_mfma(
    const float* __restrict__ X, const float* __restrict__ W,
    const float* __restrict__ bias, unsigned* __restrict__ h_u) {
    __shared__ unsigned short WTs[FDIM * WT_STRIDE];   // ~34 KB
    const int t = threadIdx.x;
    for (int idx = t; idx < FDIM * HDIM; idx += 256) {
        const int k = idx >> 7, m = idx & 127;
        WTs[m * WT_STRIDE + k] = f2bf(W[idx]);
    }
    __syncthreads();

    const int wave = t >> 6, lane = t & 63;
    const int quad = lane >> 4, sub = lane & 15;
    const int nstrips = N_V / 16;  // 6250, exact

    for (int s = blockIdx.x * 4 + wave; s < nstrips; s += GEMM_BLOCKS * 4) {
        const int row0 = s * 16;
        short8 xf[4];
        const float* xp = X + (size_t)(row0 + sub) * FDIM + quad * 8;
        #pragma unroll
        for (int kt = 0; kt < 4; ++kt) {
            const float4 a = *(const float4*)(xp + kt * 32);
            const float4 b2 = *(const float4*)(xp + kt * 32 + 4);
            short8 f;
            f[0] = (short)f2bf(a.x);  f[1] = (short)f2bf(a.y);
            f[2] = (short)f2bf(a.z);  f[3] = (short)f2bf(a.w);
            f[4] = (short)f2bf(b2.x); f[5] = (short)f2bf(b2.y);
            f[6] = (short)f2bf(b2.z); f[7] = (short)f2bf(b2.w);
            xf[kt] = f;
        }
        #pragma unroll
        for (int tile = 0; tile < 8; ++tile) {
            floatx4 acc = {0.f, 0.f, 0.f, 0.f};
            const unsigned short* wp =
                WTs + (tile * 16 + sub) * WT_STRIDE + quad * 8;
            #pragma unroll
            for (int kt = 0; kt < 4; ++kt) {
                const short8 af = *(const short8*)(wp + kt * 32);
                acc = __builtin_amdgcn_mfma_f32_16x16x32_bf16(af, xf[kt], acc,
                                                              0, 0, 0);
            }
            const int ch = tile * 16 + quad * 4;
            const float4 bb = *(const float4*)(bias + ch);
            const float c0 = acc[0] + bb.x, c1 = acc[1] + bb.y;
            const float c2 = acc[2] + bb.z, c3 = acc[3] + bb.w;
            const unsigned lo = (unsigned)f2bf(c0) | ((unsigned)f2bf(c1) << 16);
            const unsigned hi = (unsigned)f2bf(c2) | ((unsigned)f2bf(c3) << 16);
            uint2* dst = (uint2*)(h_u + (size_t)(row0 + sub) * 64 + (ch >> 1));
            *dst = make_uint2(lo, hi);
        }
    }
}

// ---------------------------------------------------------------------------
// Kernel B: per-channel sum & sumsq of bf16 h.  Vectorized: uint4 per lane
// (8 channels), shfl reduce across row-lanes, one LDS+global atomic pass.
// [R7: correctness-verified; kept through the R7 revert]
// ---------------------------------------------------------------------------
#define BN_BLOCKS 400
#define BN_RPB 250
__global__ __launch_bounds__(256) void k_bn_stats(
    const unsigned* __restrict__ h_u, float* __restrict__ sums /* [256] */) {
    const int t = threadIdx.x;
    const int c8 = t & 15;            // channel octet: ch 8*c8 .. 8*c8+7
    const int rw = t >> 4;            // 16 row lanes
    const int r0 = blockIdx.x * BN_RPB;
    const int r1 = min(r0 + BN_RPB, N_V);
    float s[8] = {0.f,0.f,0.f,0.f,0.f,0.f,0.f,0.f};
    float ss[8] = {0.f,0.f,0.f,0.f,0.f,0.f,0.f,0.f};
    for (int r = r0 + rw; r < r1; r += 16) {
        const uint4 u = *(const uint4*)(h_u + (size_t)r * 64 + c8 * 4);
        const float x0 = bf_lo(u.x), x1 = bf_hi(u.x);
        const float x2 = bf_lo(u.y), x3 = bf_hi(u.y);
        const float x4 = bf_lo(u.z), x5 = bf_hi(u.z);
        const float x6 = bf_lo(u.w), x7 = bf_hi(u.w);
        s[0]+=x0; ss[0]+=x0*x0;  s[1]+=x1; ss[1]+=x1*x1;
        s[2]+=x2; ss[2]+=x2*x2;  s[3]+=x3; ss[3]+=x3*x3;
        s[4]+=x4; ss[4]+=x4*x4;  s[5]+=x5; ss[5]+=x5*x5;
        s[6]+=x6; ss[6]+=x6*x6;  s[7]+=x7; ss[7]+=x7*x7;
    }
    #pragma unroll
    for (int k = 0; k < 8; ++k) {
        s[k]  += __shfl_xor(s[k], 16);  s[k]  += __shfl_xor(s[k], 32);
        ss[k] += __shfl_xor(ss[k], 16); ss[k] += __shfl_xor(ss[k], 32);
    }
    __shared__ float ls[128], lss[128];
    for (int k = t; k < 128; k += 256) { ls[k] = 0.f; lss[k] = 0.f; }
    __syncthreads();
    if ((t & 63) < 16) {
        #pragma unroll
        for (int k = 0; k < 8; ++k) {
            atomicAdd(&ls[c8 * 8 + k], s[k]);
            atomicAdd(&lss[c8 * 8 + k], ss[k]);
        }
    }
    __syncthreads();
    if (t < 128) {
        atomicAdd(&sums[t],       ls[t]);
        atomicAdd(&sums[128 + t], lss[t]);
    }
}

// ---------------------------------------------------------------------------
// Kernel C: finalize BN -> scale/shift
// ---------------------------------------------------------------------------
__global__ void k_bn_final(const float* __restrict__ sums,
                           const float* __restrict__ gamma,
                           const float* __restrict__ beta,
                           float* __restrict__ scale, float* __restrict__ shift) {
    const int c = threadIdx.x;
    const float inv_n = 1.0f / (float)N_V;
    const float mu  = sums[c] * inv_n;
    const float var = sums[128 + c] * inv_n - mu * mu;
    const float inv = rsqrtf(var + BN_EPS);
    const float sc  = gamma[c] * inv;
    scale[c] = sc;
    shift[c] = beta[c] - mu * sc;
}

// ---------------------------------------------------------------------------
// Kernel D: dual-direction LDS-staged chunk sort, line-aligned full-line
// flush.  One pass over (eid, vid) builds BOTH partitions.
// ---------------------------------------------------------------------------
__global__ __launch_bounds__(256) void k_sort_dual(
    const int* __restrict__ vid, const int* __restrict__ eid,
    int* __restrict__ gcntE, int* __restrict__ gcntV,
    unsigned* __restrict__ partE, unsigned* __restrict__ partV) {
    __shared__ unsigned stageE[SORT_C];          // 16 KB
    __shared__ unsigned stageV[SORT_C];          // 16 KB
    __shared__ int histE[NB_E], curE[NB_E], offsE[NB_E], gbaseE[NB_E];
    __shared__ int histV[NB_V], curV[NB_V], offsV[NB_V], gbaseV[NB_V];
    __shared__ int partial[256];
    const int t = threadIdx.x;
    const int p0 = blockIdx.x * SORT_C;
    const int n = min(SORT_C, N_P - p0);

    for (int k = t; k < NB_E; k += 256) histE[k] = 0;
    for (int k = t; k < NB_V; k += 256) histV[k] = 0;
    __syncthreads();
    for (int i = t; i < n; i += 256) {
        atomicAdd(&histE[((unsigned)eid[p0 + i]) >> EB_SHIFT], 1);
        atomicAdd(&histV[((unsigned)vid[p0 + i]) >> VB_SHIFT], 1);
    }
    __syncthreads();
    // scan E
    {
        constexpr int G = (NB_E + 255) / 256;
        int loc[G]; int s = 0;
        #pragma unroll
        for (int g = 0; g < G; ++g) {
            int idx = t * G + g; loc[g] = s;
            if (idx < NB_E) s += histE[idx];
        }
        partial[t] = s;
        __syncthreads();
        for (int d = 1; d < 256; d <<= 1) {
            int x = (t >= d) ? partial[t - d] : 0;
            __syncthreads(); partial[t] += x; __syncthreads();
        }
        const int base = t ? partial[t - 1] : 0;
        #pragma unroll
        for (int g = 0; g < G; ++g) {
            int idx = t * G + g;
            if (idx < NB_E) { offsE[idx] = base + loc[g]; curE[idx] = base + loc[g]; }
        }
        __syncthreads();
    }
    // scan V
    {
        constexpr int G = (NB_V + 255) / 256;
        int loc[G]; int s = 0;
        #pragma unroll
        for (int g = 0; g < G; ++g) {
            int idx = t * G + g; loc[g] = s;
            if (idx < NB_V) s += histV[idx];
        }
        partial[t] = s;
        __syncthreads();
        for (int d = 1; d < 256; d <<= 1) {
            int x = (t >= d) ? partial[t - d] : 0;
            __syncthreads(); partial[t] += x; __syncthreads();
        }
        const int base = t ? partial[t - 1] : 0;
        #pragma unroll
        for (int g = 0; g < G; ++g) {
            int idx = t * G + g;
            if (idx < NB_V) { offsV[idx] = base + loc[g]; curV[idx] = base + loc[g]; }
        }
        __syncthreads();
    }
    // place both directions
    for (int i = t; i < n; i += 256) {
        const int ev = eid[p0 + i], vv = vid[p0 + i];
        const unsigned pkE = ((unsigned)(ev & 63) << 17) | (unsigned)vv;
        stageE[atomicAdd(&curE[(unsigned)ev >> EB_SHIFT], 1)] = pkE;
        const unsigned pkV = ((unsigned)(vv & 255) << 15) | (unsigned)ev;
        stageV[atomicAdd(&curV[(unsigned)vv >> VB_SHIFT], 1)] = pkV;
    }
    __syncthreads();
    // allocate line-aligned global space
    for (int k = t; k < NB_E; k += 256) {
        const int c = histE[k];
        gbaseE[k] = c ? atomicAdd(&gcntE[k], (c + 15) & ~15) : 0;
    }
    for (int k = t; k < NB_V; k += 256) {
        const int c = histV[k];
        gbaseV[k] = c ? atomicAdd(&gcntV[k], (c + 15) & ~15) : 0;
    }
    __syncthreads();
    // flush E
    for (int k = t >> 3; k < NB_E; k += 32) {
        const int c = histE[k];
        if (c == 0) continue;
        int cpad = (c + 15) & ~15;
        const int gb = gbaseE[k];
        if (gb >= EB_REGION) continue;
        cpad = min(cpad, EB_REGION - gb);
        unsigned* dst = partE + (size_t)k * EB_REGION + gb;
        const int lo = offsE[k];
        for (int j = t & 7; j < cpad; j += 8)
            dst[j] = (j < c) ? stageE[lo + j] : SENTINEL;
    }
    // flush V
    for (int k = t >> 3; k < NB_V; k += 32) {
        const int c = histV[k];
        if (c == 0) continue;
        int cpad = (c + 15) & ~15;
        const int gb = gbaseV[k];
        if (gb >= VB_REGION) continue;
        cpad = min(cpad, VB_REGION - gb);
        unsigned* dst = partV + (size_t)k * VB_REGION + gb;
        const int lo = offsV[k];
        for (int j = t & 7; j < cpad; j += 8)
            dst[j] = (j < c) ? stageV[lo + j] : SENTINEL;
    }
}

// ---------------------------------------------------------------------------
// Kernel E: bucket region -> compact sorted CSR (adjacency + seg off/cnt).
// [R7 lesson: replacing this with LDS-atomic bucket accumulation is 27x
// slower (1.2M LDS bank conflicts, 12.8M serialized atomics) — keep the
// sort -> register-reduce structure.]
// ---------------------------------------------------------------------------
template <int NKEY, int PACK_SHIFT, int CAP, int REGION, int STRIDE>
__global__ __launch_bounds__(256) void k_csr(
    const unsigned* __restrict__ part, const int* __restrict__ gcnt,
    int nkeys_total, int* __restrict__ segoff, int* __restrict__ segcnt,
    unsigned* __restrict__ csr) {
    __shared__ unsigned A[CAP];
    __shared__ unsigned B[CAP];
    __shared__ int hist[NKEY], offs[NKEY + 1], cur[NKEY];
    __shared__ int lcur;
    const int bkt = blockIdx.x;
    const int t = threadIdx.x;
    const int lane = t & 63;
    const unsigned mask = (1u << PACK_SHIFT) - 1u;
    const int tot = min(gcnt[bkt], REGION);
    const unsigned* src = part + (size_t)bkt * REGION;

    if (t == 0) lcur = 0;
    for (int k = t; k < NKEY; k += 256) hist[k] = 0;
    __syncthreads();
    for (int i = t; i < ((tot + 255) & ~255); i += 256) {
        unsigned a = (i < tot) ? src[i] : SENTINEL;
        const bool valid = (a != SENTINEL);
        const unsigned long long bal = __ballot(valid);
        int wbase = 0;
        if (lane == 0) wbase = atomicAdd(&lcur, __popcll(bal));
        wbase = __shfl(wbase, 0);
        if (valid) {
            const int pos = wbase + __popcll(bal & ((1ull << lane) - 1ull));
            if (pos < CAP) A[pos] = a;
        }
    }
    __syncthreads();
    const int total = min(lcur, CAP);
    for (int i = t; i < total; i += 256)
        atomicAdd(&hist[A[i] >> PACK_SHIFT], 1);
    __syncthreads();
    if (t == 0) {
        int acc = 0;
        for (int k = 0; k < NKEY; ++k) { offs[k] = acc; acc += hist[k]; }
        offs[NKEY] = acc;
    }
    for (int k = t; k < NKEY; k += 256) cur[k] = 0;
    __syncthreads();
    for (int i = t; i < total; i += 256) {
        const unsigned a = A[i];
        const int k = a >> PACK_SHIFT;
        const int pos = offs[k] + atomicAdd(&cur[k], 1);
        B[pos] = a & mask;
    }
    __syncthreads();
    unsigned* dst = csr + (size_t)bkt * STRIDE;
    for (int i = t; i < total; i += 256) dst[i] = B[i];
    for (int k = t; k < NKEY; k += 256) {
        const int g = bkt * NKEY + k;
        if (g < nkeys_total) {
            segoff[g] = bkt * STRIDE + offs[k];
            segcnt[g] = hist[k];
        }
    }
}

// ---------------------------------------------------------------------------
// Kernel F: per-edge gather-reduce, CHANNEL-HALF split across XCD groups.
// blockIdx%8 selects the XCD; XCDs 0-3 process channels 0..63 (first 128-B
// line of each row), XCDs 4-7 process channels 64..127.  Each XCD's L2
// holds only 128 B per touched row, cutting per-XCD compulsory fetch.
// One wave per (edge, half): 16 lanes/row, uint2 (4 ch) per lane,
// 8 rows-in-flight main loop, LDS index prefetch.  [measured R5/R6]
// ---------------------------------------------------------------------------
__global__ __launch_bounds__(256) void k_edge_gather(
    const unsigned* __restrict__ h_u, const unsigned* __restrict__ csrE,
    const int* __restrict__ eoff, const int* __restrict__ ecnt,
    const float* __restrict__ scale, const float* __restrict__ shift,
    unsigned* __restrict__ xe_u) {
    __shared__ int ib[4][EIDX_CAP];
    const int b = blockIdx.x;                   // 0 .. 2*(N_E/4)-1
    const int xcd = b & 7;
    const int half = xcd >> 2;                  // channel half 0/1
    const int grp = (b >> 3) * 4 + (xcd & 3);   // edge group 0..N_E/4-1
    const int wave = threadIdx.x >> 6;
    const int e = grp * 4 + wave;
    const int l = threadIdx.x & 63;
    const int rg = l >> 4, c = l & 15;          // row-in-group, channel-pair
    const int wbase = half * 32 + 2 * c;        // word offset within row
    int o = 0, n = 0;
    if (e < N_E) { o = eoff[e]; n = ecnt[e]; }
    const int nc = min(n, EIDX_CAP);
    int* mi = ib[wave];
    for (int i = l; i < nc; i += 64) mi[i] = csrE[o + i];
    __syncthreads();

    float s[4] = {0.f, 0.f, 0.f, 0.f};
    int j = 0;
    for (; j + 31 < nc; j += 32) {
        const int r0 = mi[j + rg],      r1 = mi[j + 4 + rg];
        const int r2 = mi[j + 8 + rg],  r3 = mi[j + 12 + rg];
        const int r4 = mi[j + 16 + rg], r5 = mi[j + 20 + rg];
        const int r6 = mi[j + 24 + rg], r7 = mi[j + 28 + rg];
        const uint2 u0 = *(const uint2*)(h_u + (size_t)r0 * 64 + wbase);
        const uint2 u1 = *(const uint2*)(h_u + (size_t)r1 * 64 + wbase);
        const uint2 u2 = *(const uint2*)(h_u + (size_t)r2 * 64 + wbase);
        const uint2 u3 = *(const uint2*)(h_u + (size_t)r3 * 64 + wbase);
        const uint2 u4 = *(const uint2*)(h_u + (size_t)r4 * 64 + wbase);
        const uint2 u5 = *(const uint2*)(h_u + (size_t)r5 * 64 + wbase);
        const uint2 u6 = *(const uint2*)(h_u + (size_t)r6 * 64 + wbase);
        const uint2 u7 = *(const uint2*)(h_u + (size_t)r7 * 64 + wbase);
        acc4(s, u0); acc4(s, u1); acc4(s, u2); acc4(s, u3);
        acc4(s, u4); acc4(s, u5); acc4(s, u6); acc4(s, u7);
    }
    for (; j + 15 < nc; j += 16) {
        const int r0 = mi[j + rg],     r1 = mi[j + 4 + rg];
        const int r2 = mi[j + 8 + rg], r3 = mi[j + 12 + rg];
        const uint2 u0 = *(const uint2*)(h_u + (size_t)r0 * 64 + wbase);
        const uint2 u1 = *(const uint2*)(h_u + (size_t)r1 * 64 + wbase);
        const uint2 u2 = *(const uint2*)(h_u + (size_t)r2 * 64 + wbase);
        const uint2 u3 = *(const uint2*)(h_u + (size_t)r3 * 64 + wbase);
        acc4(s, u0); acc4(s, u1); acc4(s, u2); acc4(s, u3);
    }
    for (; j < nc; j += 4) {
        if (j + rg < nc) {
            const int r = mi[j + rg];
            const uint2 u = *(const uint2*)(h_u + (size_t)r * 64 + wbase);
            acc4(s, u);
        }
    }
    // overflow path (n > EIDX_CAP), statistically negligible but correct
    for (int jj = nc; jj < n; jj += 4) {
        if (jj + rg < n) {
            const int r = csrE[o + jj + rg];
            const uint2 u = *(const uint2*)(h_u + (size_t)r * 64 + wbase);
            acc4(s, u);
        }
    }
    #pragma unroll
    for (int k = 0; k < 4; ++k) {
        s[k] += __shfl_xor(s[k], 16);
        s[k] += __shfl_xor(s[k], 32);
    }
    if (e < N_E && rg == 0) {
        float m[4] = {0.f, 0.f, 0.f, 0.f};
        if (n > 0) {
            const float rc = 1.0f / (float)n;
            const float4 sc4 = ((const float4*)scale)[half * 16 + c];
            const float4 sh4 = ((const float4*)shift)[half * 16 + c];
            m[0] = sc4.x * s[0] * rc + sh4.x;
            m[1] = sc4.y * s[1] * rc + sh4.y;
            m[2] = sc4.z * s[2] * rc + sh4.z;
            m[3] = sc4.w * s[3] * rc + sh4.w;
        }
        uint2 pk;
        pk.x = (unsigned)f2bf(m[0]) | ((unsigned)f2bf(m[1]) << 16);
        pk.y = (unsigned)f2bf(m[2]) | ((unsigned)f2bf(m[3]) << 16);
        *(uint2*)(xe_u + (size_t)e * 64 + wbase) = pk;
    }
}

// ---------------------------------------------------------------------------
// Kernel G: per-vertex gather-reduce + ReLU.  Full-row uint4, one wave per
// vertex, LDS index prefetch, 16-row main loop.  [measured R6: 49.5 us]
// ---------------------------------------------------------------------------
__global__ __launch_bounds__(256) void k_vert_gather(
    const unsigned* __restrict__ xe_u, const unsigned* __restrict__ csrV,
    const int* __restrict__ voff, const int* __restrict__ vcnt,
    float* __restrict__ out) {
    __shared__ int ib[4][VIDX_CAP];
    const int wave = threadIdx.x >> 6;
    const int v = blockIdx.x * 4 + wave;
    const int l = threadIdx.x & 63;
    const int g = l >> 4, c = l & 15;
    int o = 0, n = 0;
    if (v < N_V) { o = voff[v]; n = vcnt[v]; }
    const int nc = min(n, VIDX_CAP);
    int* mi = ib[wave];
    for (int i = l; i < nc; i += 64) mi[i] = csrV[o + i];
    __syncthreads();

    float s[8] = {0.f, 0.f, 0.f, 0.f, 0.f, 0.f, 0.f, 0.f};
    int j = 0;
    for (; j + 15 < nc; j += 16) {
        const int r0 = mi[j + g],     r1 = mi[j + 4 + g];
        const int r2 = mi[j + 8 + g], r3 = mi[j + 12 + g];
        const uint4 u0 = *(const uint4*)(xe_u + (size_t)r0 * 64 + 4 * c);
        const uint4 u1 = *(const uint4*)(xe_u + (size_t)r1 * 64 + 4 * c);
        const uint4 u2 = *(const uint4*)(xe_u + (size_t)r2 * 64 + 4 * c);
        const uint4 u3 = *(const uint4*)(xe_u + (size_t)r3 * 64 + 4 * c);
        acc8(s, u0); acc8(s, u1); acc8(s, u2); acc8(s, u3);
    }
    for (; j < nc; j += 4) {
        if (j + g < nc) {
            const int r = mi[j + g];
            const uint4 u = *(const uint4*)(xe_u + (size_t)r * 64 + 4 * c);
            acc8(s, u);
        }
    }
    // overflow path (n > VIDX_CAP), statistically negligible but correct
    for (int jj = nc; jj < n; jj += 4) {
        if (jj + g < n) {
            const int r = csrV[o + jj + g];
            const uint4 u = *(const uint4*)(xe_u + (size_t)r * 64 + 4 * c);
            acc8(s, u);
        }
    }
    #pragma unroll
    for (int k = 0; k < 8; ++k) {
        s[k] += __shfl_xor(s[k], 16);
        s[k] += __shfl_xor(s[k], 32);
    }
    if (v < N_V && g == 0) {
        const float rc = 1.0f / (float)max(n, 1);
        float4 r0, r1;
        r0.x = fmaxf(s[0] * rc, 0.f);
        r0.y = fmaxf(s[1] * rc, 0.f);
        r0.z = fmaxf(s[2] * rc, 0.f);
        r0.w = fmaxf(s[3] * rc, 0.f);
        r1.x = fmaxf(s[4] * rc, 0.f);
        r1.y = fmaxf(s[5] * rc, 0.f);
        r1.z = fmaxf(s[6] * rc, 0.f);
        r1.w = fmaxf(s[7] * rc, 0.f);
        ((float4*)out)[(size_t)v * 32 + 2 * c]     = r0;
        ((float4*)out)[(size_t)v * 32 + 2 * c + 1] = r1;
    }
}

// ---------------------------------------------------------------------------
extern "C" void kernel_launch(void* const* d_in, const int* in_sizes, int n_in,
                              void* d_out, int out_size, void* d_ws, size_t ws_size,
                              hipStream_t stream) {
    const float* X     = (const float*)d_in[0];
    const int*   vid   = (const int*)d_in[1];
    const int*   eid   = (const int*)d_in[2];
    const float* W     = (const float*)d_in[3];
    const float* b     = (const float*)d_in[4];
    const float* gamma = (const float*)d_in[5];
    const float* beta  = (const float*)d_in[6];
    float* out = (float*)d_out;

    // workspace layout
    char* ws = (char*)d_ws;
    unsigned* h_u   = (unsigned*)ws;  ws += (size_t)N_V * 64 * 4;            // 25.6 MB
    unsigned* xe_u  = (unsigned*)ws;  ws += (size_t)N_E * 64 * 4;            //  5.1 MB
    unsigned* partE = (unsigned*)ws;  ws += (size_t)NB_E * EB_REGION * 4;    // 11.5 MB
    unsigned* partV = (unsigned*)ws;  ws += (size_t)NB_V * VB_REGION * 4;    // 12.8 MB
    unsigned* csrE  = (unsigned*)ws;  ws += (size_t)NB_E * EB_SORT * 4;      //  7.4 MB
    unsigned* csrV  = (unsigned*)ws;  ws += (size_t)NB_V * VB_SORT * 4;      //  7.2 MB
    int* eoff = (int*)ws;             ws += (size_t)N_E * 4;
    int* ecnt = (int*)ws;             ws += (size_t)N_E * 4;
    int* voff = (int*)ws;             ws += (size_t)N_V * 4;
    int* vcnt = (int*)ws;             ws += (size_t)N_V * 4;
    // --- zeroed region ---
    char* zbase = ws;
    int*   gcntE = (int*)ws;          ws += (size_t)NB_E * 4;
    int*   gcntV = (int*)ws;          ws += (size_t)NB_V * 4;
    float* sums  = (float*)ws;        ws += 256 * 4;
    // --- end zeroed region ---
    float* scale = (float*)ws;        ws += 128 * 4;
    float* shift = (float*)ws;        ws += 128 * 4;

    hipMemsetAsync(zbase, 0, (size_t)((char*)scale - zbase), stream);

    k_gemm_mfma<<<GEMM_BLOCKS, 256, 0, stream>>>(X, W, b, h_u);
    k_bn_stats<<<BN_BLOCKS, 256, 0, stream>>>(h_u, sums);
    k_bn_final<<<1, 128, 0, stream>>>(sums, gamma, beta, scale, shift);

    k_sort_dual<<<SORT_BLOCKS, 256, 0, stream>>>(vid, eid, gcntE, gcntV,
                                                 partE, partV);

    k_csr<64, 17, EB_SORT, EB_REGION, EB_SORT>
        <<<NB_E, 256, 0, stream>>>(partE, gcntE, N_E, eoff, ecnt, csrE);
    k_csr<256, 15, VB_SORT, VB_REGION, VB_SORT>
        <<<NB_V, 256, 0, stream>>>(partV, gcntV, N_V, voff, vcnt, csrV);

    // edge: 2 channel-halves x (N_E/4) groups; blockIdx%8 pins XCD,
    // XCDs 0-3 -> half 0, XCDs 4-7 -> half 1.
    k_edge_gather<<<(N_E / 4) * 2, 256, 0, stream>>>(h_u, csrE, eoff, ecnt,
                                                     scale, shift, xe_u);
    // vertex: full-row, one wave per vertex
    k_vert_gather<<<(N_V + 3) / 4, 256, 0, stream>>>(xe_u, csrV, voff, vcnt,
                                                     out);
}